// Round 4
// baseline (411.845 us; speedup 1.0000x reference)
//
#include <hip/hip_runtime.h>
#include <math.h>

namespace {

typedef short s16;
typedef short s16x8 __attribute__((ext_vector_type(8)));
typedef float f32x4 __attribute__((ext_vector_type(4)));

constexpr int B   = 2;
constexpr int S   = 2048;
constexpr int H   = 2048;
constexpr int NH  = 16;
constexpr int NKV = 4;
constexpr int HD  = 128;
constexpr int WIN = 1024;
constexpr int M   = B * S;       // 4096

// ---- fp32 -> bf16 (RNE) as raw short ----
__device__ inline s16 f2bs(float x) {
    unsigned u = __float_as_uint(x);
    u += 0x7fffu + ((u >> 16) & 1u);
    return (s16)(u >> 16);
}
// ---- bf16 bits -> fp32 ----
__device__ inline float bs2f(s16 v) {
    return __uint_as_float(((unsigned)(unsigned short)v) << 16);
}

__device__ inline void gload_lds16(const void* g, void* l) {
    __builtin_amdgcn_global_load_lds(
        (const __attribute__((address_space(1))) void*)g,
        (__attribute__((address_space(3))) void*)l, 16, 0, 0);
}

// ---------- fp32 -> bf16 cast, 8 elems/thread ----------
__global__ __launch_bounds__(256) void cast_kernel(const float* __restrict__ X,
                                                   s16* __restrict__ Y, int n8) {
    int i = blockIdx.x * 256 + threadIdx.x;
    if (i >= n8) return;
    const float4* p = (const float4*)X + (size_t)i * 2;
    float4 a = p[0], b = p[1];
    s16x8 v;
    v[0] = f2bs(a.x); v[1] = f2bs(a.y); v[2] = f2bs(a.z); v[3] = f2bs(a.w);
    v[4] = f2bs(b.x); v[5] = f2bs(b.y); v[6] = f2bs(b.z); v[7] = f2bs(b.w);
    *(s16x8*)(Y + (size_t)i * 8) = v;
}

// ---------- W[K][N] fp32 -> WT[N][K] bf16 ----------
__global__ __launch_bounds__(256) void transpose_cast(const float* __restrict__ W,
                                                      s16* __restrict__ WT,
                                                      int K, int N) {
    __shared__ float tile[64][65];
    int c = threadIdx.x & 63, r4 = threadIdx.x >> 6;
    int nb = blockIdx.x * 64, kb = blockIdx.y * 64;
    #pragma unroll
    for (int i = 0; i < 16; ++i) {
        int r = r4 + i * 4;
        tile[r][c] = W[(size_t)(kb + r) * N + nb + c];
    }
    __syncthreads();
    #pragma unroll
    for (int i = 0; i < 16; ++i) {
        int r = r4 + i * 4;
        WT[(size_t)(nb + r) * K + kb + c] = f2bs(tile[c][r]);
    }
}

// ---------- bf16 MFMA GEMM: C[M,N] = A[M,K] @ BT[N,K]^T ----------
// 128x128 tile, BK=32, 4 waves (2x2), 4x4 16x16x32 frags per wave.
// LDS XOR-swizzled at 16B granularity (superrow=128B, slot'=slot^(sr&7)).
template <bool BF16OUT>
__global__ __launch_bounds__(256) void gemm_bf16(const s16* __restrict__ A,
                                                 const s16* __restrict__ BT,
                                                 void* __restrict__ Cv,
                                                 int Ndim, int Kdim) {
    __shared__ __align__(16) s16 As[128 * 32];
    __shared__ __align__(16) s16 Bs[128 * 32];

    const int t    = threadIdx.x;
    const int lane = t & 63;
    const int wid  = t >> 6;
    const int wr   = wid >> 1;
    const int wc   = wid & 1;
    const int rowBase = blockIdx.y * 128;
    const int colBase = blockIdx.x * 128;

    const s16* Ab = A  + (size_t)rowBase * Kdim;
    const s16* Bb = BT + (size_t)colBase * Kdim;

    f32x4 acc[4][4];
    #pragma unroll
    for (int m = 0; m < 4; ++m)
        #pragma unroll
        for (int n = 0; n < 4; ++n)
            acc[m][n] = (f32x4)0.f;

    for (int k0 = 0; k0 < Kdim; k0 += 32) {
        #pragma unroll
        for (int i = 0; i < 2; ++i) {
            int lc = i * 256 + t;             // 16B chunk 0..511
            int sr = lc >> 3;                 // 128B superrow
            int cc = (lc & 7) ^ (sr & 7);     // source chunk in superrow
            int r  = (sr << 1) | (cc >> 2);
            int kg = cc & 3;
            const s16* ga = Ab + (size_t)r * Kdim + k0 + kg * 8;
            const s16* gb = Bb + (size_t)r * Kdim + k0 + kg * 8;
            char* la = (char*)As + i * 4096 + wid * 1024;
            char* lb = (char*)Bs + i * 4096 + wid * 1024;
            gload_lds16(ga, la);
            gload_lds16(gb, lb);
        }
        __syncthreads();

        s16x8 af[4], bfr[4];
        #pragma unroll
        for (int m = 0; m < 4; ++m) {
            int r  = wr * 64 + m * 16 + (lane & 15);
            int sr = r >> 1;
            int c  = ((r & 1) << 2) | (lane >> 4);
            int cs = c ^ (sr & 7);
            af[m] = *(const s16x8*)(As + sr * 64 + cs * 8);
        }
        #pragma unroll
        for (int n = 0; n < 4; ++n) {
            int r  = wc * 64 + n * 16 + (lane & 15);
            int sr = r >> 1;
            int c  = ((r & 1) << 2) | (lane >> 4);
            int cs = c ^ (sr & 7);
            bfr[n] = *(const s16x8*)(Bs + sr * 64 + cs * 8);
        }
        #pragma unroll
        for (int m = 0; m < 4; ++m)
            #pragma unroll
            for (int n = 0; n < 4; ++n)
                acc[m][n] = __builtin_amdgcn_mfma_f32_16x16x32_bf16(af[m], bfr[n], acc[m][n], 0, 0, 0);

        __syncthreads();
    }

    // C/D: col=lane&15, row=(lane>>4)*4+reg (m89-verified)
    #pragma unroll
    for (int m = 0; m < 4; ++m) {
        int row = rowBase + wr * 64 + m * 16 + ((lane >> 4) << 2);
        #pragma unroll
        for (int n = 0; n < 4; ++n) {
            int col = colBase + wc * 64 + n * 16 + (lane & 15);
            if (BF16OUT) {
                s16* cp = (s16*)Cv + (size_t)row * Ndim + col;
                #pragma unroll
                for (int j = 0; j < 4; ++j)
                    cp[(size_t)j * Ndim] = f2bs(acc[m][n][j]);
            } else {
                float* cp = (float*)Cv + (size_t)row * Ndim + col;
                #pragma unroll
                for (int j = 0; j < 4; ++j)
                    cp[(size_t)j * Ndim] = acc[m][n][j];
            }
        }
    }
}

// ---------- RoPE in-place on bf16, 8 j-values per thread ----------
// X rows: rowStride bf16; head hh at cols hh*128. scale folded into output.
__global__ __launch_bounds__(256) void rope_kernel(s16* __restrict__ X, int nHmask,
                                                   int rowShift, int rowStride,
                                                   float scale, int total) {
    int idx = blockIdx.x * 256 + threadIdx.x;
    if (idx >= total) return;
    int jc  = idx & 7;                 // j-chunk of 8
    int hh  = (idx >> 3) & nHmask;
    int row = idx >> rowShift;
    int s   = row & (S - 1);

    s16* base = X + (size_t)row * rowStride + hh * HD;
    s16x8 a = *(const s16x8*)(base + jc * 8);
    s16x8 b = *(const s16x8*)(base + 64 + jc * 8);
    s16x8 na, nb;
    #pragma unroll
    for (int i = 0; i < 8; ++i) {
        int j = jc * 8 + i;
        float f = (float)s * exp2f(-(float)j * 0.2076205059302203f);  // s*10000^(-j/64)
        float sn, c;
        __sincosf(f, &sn, &c);
        float x1 = bs2f(a[i]), x2 = bs2f(b[i]);
        na[i] = f2bs((x1 * c - x2 * sn) * scale);
        nb[i] = f2bs((x2 * c + x1 * sn) * scale);
    }
    *(s16x8*)(base + jc * 8) = na;
    *(s16x8*)(base + 64 + jc * 8) = nb;
}

// ---------- V transpose: KVb[M][1024] (V at col 512+kvh*128+d) -> VT[b][kvh][128][S] ----------
__global__ __launch_bounds__(256) void vtrans(const s16* __restrict__ KVb,
                                              s16* __restrict__ VT) {
    __shared__ s16 tl[64][72];
    const int t  = threadIdx.x;
    const int c8 = (t & 7) * 8;       // d-chunk within 64
    const int r  = t >> 3;            // 0..31 (s dir)
    const int s0 = blockIdx.x * 64;
    const int z  = blockIdx.y;        // bk*2 + dhalf
    const int bk = z >> 1;            // b*4+kvh
    const int d0 = (z & 1) * 64;
    const int b  = bk >> 2, kvh = bk & 3;

    #pragma unroll
    for (int i = 0; i < 2; ++i) {
        int row = r + i * 32;
        *(s16x8*)&tl[row][c8] =
            *(const s16x8*)(KVb + (size_t)(b * S + s0 + row) * 1024 + 512 + kvh * HD + d0 + c8);
    }
    __syncthreads();
    #pragma unroll
    for (int i = 0; i < 2; ++i) {
        int drow = r + i * 32;        // d within 64
        s16x8 v;
        #pragma unroll
        for (int k = 0; k < 8; ++k) v[k] = tl[c8 + k][drow];
        *(s16x8*)(VT + (size_t)(bk * 128 + d0 + drow) * S + s0 + c8) = v;
    }
}

// ---------- MFMA flash attention ----------
// Block: 4 waves = 4 q-heads of one kv-group, one 16-row q-tile.
// grid = B*NKV*(S/16) = 1024. Q pre-scaled by 1/sqrt(128) (in rope).
__global__ __launch_bounds__(256) void attn_mfma(const s16* __restrict__ Q,
                                                 const s16* __restrict__ KV,
                                                 const s16* __restrict__ VT,
                                                 s16* __restrict__ O) {
    __shared__ __align__(16) s16 Kl[32 * 128];   // [kv][k], 16B-slot swizzled: slot^(r&15)
    __shared__ __align__(16) s16 Vl[128 * 32];   // [d][kv], slot swizzled: slot^((d>>1)&3)
    __shared__ __align__(16) s16 Pl[4][16 * 40]; // per-wave P, 80B-padded rows

    const int t    = threadIdx.x;
    const int lane = t & 63;
    const int wid  = t >> 6;
    const int g    = lane >> 4;
    const int cc   = lane & 15;
    const int bid  = blockIdx.x;
    const int qt   = bid & 127;
    const int kvh  = (bid >> 7) & 3;
    const int b    = bid >> 9;
    const int qbase = qt * 16;
    const int h    = kvh * 4 + wid;

    // Q A-frags: lane holds row=cc, k=kc*32+g*8..+7
    s16x8 qf[4];
    #pragma unroll
    for (int kc = 0; kc < 4; ++kc)
        qf[kc] = *(const s16x8*)(Q + (size_t)(b * S + qbase + cc) * 2048 + h * HD + kc * 32 + g * 8);

    float m_[4], l_[4];
    f32x4 o_[8];
    #pragma unroll
    for (int j = 0; j < 4; ++j) { m_[j] = -1e30f; l_[j] = 0.f; }
    #pragma unroll
    for (int dt = 0; dt < 8; ++dt) o_[dt] = (f32x4)0.f;

    const int kvstart = qbase >= WIN ? qbase - WIN : 0;
    const int nt = (qbase + 16 - kvstart + 31) >> 5;

    for (int it = 0; it < nt; ++it) {
        const int kvb = kvstart + it * 32;

        // ---- stage K tile (8KB) + V tile (8KB) ----
        #pragma unroll
        for (int i = 0; i < 2; ++i) {
            int lc = i * 256 + t;
            {   // K: row r (256B), 16 slots; source chunk = slot ^ (r&15)
                int r = lc >> 4, slot = lc & 15;
                int ch = slot ^ (r & 15);
                int kvr = kvb + r; if (kvr > S - 1) kvr = S - 1;
                const s16* src = KV + (size_t)(b * S + kvr) * 1024 + kvh * HD + ch * 8;
                gload_lds16(src, (char*)Kl + i * 4096 + wid * 1024);
            }
            {   // V: row d (64B), 4 slots; source chunk = slot ^ ((d>>1)&3)
                int d = lc >> 2, slot = lc & 3;
                int ch = slot ^ ((d >> 1) & 3);
                int col = kvb + ch * 8; if (col > S - 8) col = S - 8;
                const s16* src = VT + (size_t)((b * 4 + kvh) * 128 + d) * S + col;
                gload_lds16(src, (char*)Vl + i * 4096 + wid * 1024);
            }
        }
        __syncthreads();

        // ---- QK^T: S[16q][32kv] as 2 C-frags ----
        f32x4 sv[2];
        sv[0] = (f32x4)0.f; sv[1] = (f32x4)0.f;
        #pragma unroll
        for (int tt = 0; tt < 2; ++tt) {
            #pragma unroll
            for (int kc = 0; kc < 4; ++kc) {
                int r = tt * 16 + cc;
                int slot = (kc * 4 + g) ^ (r & 15);
                s16x8 kf = *(const s16x8*)(Kl + r * 128 + slot * 8);
                sv[tt] = __builtin_amdgcn_mfma_f32_16x16x32_bf16(qf[kc], kf, sv[tt], 0, 0, 0);
            }
        }

        // ---- mask + online softmax (lane: col kv=kvb+tt*16+cc, row q=qbase+4g+j) ----
        #pragma unroll
        for (int j = 0; j < 4; ++j) {
            int qp = qbase + 4 * g + j;
            int kv0 = kvb + cc, kv1 = kvb + 16 + cc;
            float s0v = (kv0 <= qp && qp - kv0 <= WIN) ? sv[0][j] : -1e30f;
            float s1v = (kv1 <= qp && qp - kv1 <= WIN) ? sv[1][j] : -1e30f;

            float mx = fmaxf(s0v, s1v);
            #pragma unroll
            for (int off = 1; off < 16; off <<= 1) mx = fmaxf(mx, __shfl_xor(mx, off));
            float mn = fmaxf(m_[j], mx);
            float alpha = __expf(m_[j] - mn);
            m_[j] = mn;

            float p0 = __expf(s0v - mn);
            float p1 = __expf(s1v - mn);
            float ps = p0 + p1;
            #pragma unroll
            for (int off = 1; off < 16; off <<= 1) ps += __shfl_xor(ps, off);
            l_[j] = l_[j] * alpha + ps;

            Pl[wid][(4 * g + j) * 40 + cc]      = f2bs(p0);
            Pl[wid][(4 * g + j) * 40 + 16 + cc] = f2bs(p1);

            #pragma unroll
            for (int dt = 0; dt < 8; ++dt) o_[dt][j] *= alpha;
        }
        __syncthreads();   // P visible (also keeps waves in step before restage)

        // ---- PV: O[16q][128d] += P[16q][32kv] @ V[32kv][128d] ----
        s16x8 pa = *(const s16x8*)(&Pl[wid][cc * 40 + g * 8]);
        #pragma unroll
        for (int dt = 0; dt < 8; ++dt) {
            int d = dt * 16 + cc;
            int slot = g ^ ((d >> 1) & 3);
            s16x8 vf = *(const s16x8*)(Vl + d * 32 + slot * 8);
            o_[dt] = __builtin_amdgcn_mfma_f32_16x16x32_bf16(pa, vf, o_[dt], 0, 0, 0);
        }
        __syncthreads();   // LDS reads done before next stage
    }

    // ---- normalize + store (scalar bf16, coalesced in 16-lane groups) ----
    #pragma unroll
    for (int j = 0; j < 4; ++j) {
        float inv = 1.0f / l_[j];
        size_t rb = (size_t)(b * S + qbase + 4 * g + j) * 2048 + h * HD;
        #pragma unroll
        for (int dt = 0; dt < 8; ++dt)
            O[rb + dt * 16 + cc] = f2bs(o_[dt][j] * inv);
    }
}

}  // namespace

extern "C" void kernel_launch(void* const* d_in, const int* in_sizes, int n_in,
                              void* d_out, int out_size, void* d_ws, size_t ws_size,
                              hipStream_t stream) {
    const float* hs = (const float*)d_in[0];
    const float* Wq = (const float*)d_in[1];
    const float* Wk = (const float*)d_in[2];
    const float* Wv = (const float*)d_in[3];
    const float* Wo = (const float*)d_in[4];
    float* out = (float*)d_out;

    // Workspace (bf16 as s16), 64 MB total:
    // hsb[M*2048] (reused as AOb) | WqT[2048*2048] | WkvT[1024*2048] | WoT[2048*2048] |
    // Qb[M*2048] | KVb[M*1024] | VT[8*128*2048]
    char* p = (char*)d_ws;
    s16* hsb  = (s16*)p;  p += (size_t)M * 2048 * 2;
    s16* WqT  = (s16*)p;  p += (size_t)2048 * 2048 * 2;
    s16* WkvT = (s16*)p;  p += (size_t)1024 * 2048 * 2;
    s16* WoT  = (s16*)p;  p += (size_t)2048 * 2048 * 2;
    s16* Qb   = (s16*)p;  p += (size_t)M * 2048 * 2;
    s16* KVb  = (s16*)p;  p += (size_t)M * 1024 * 2;
    s16* VT   = (s16*)p;
    s16* AOb  = hsb;   // reuse after projections

    dim3 blk(256);
    const float qscale = 0.08838834764831845f;  // 1/sqrt(128)

    cast_kernel<<<(M * H / 8 + 255) / 256, blk, 0, stream>>>(hs, hsb, M * H / 8);
    transpose_cast<<<dim3(2048 / 64, 2048 / 64), blk, 0, stream>>>(Wq, WqT, 2048, 2048);
    transpose_cast<<<dim3(512 / 64, 2048 / 64), blk, 0, stream>>>(Wk, WkvT, 2048, 512);
    transpose_cast<<<dim3(512 / 64, 2048 / 64), blk, 0, stream>>>(Wv, WkvT + (size_t)512 * 2048, 2048, 512);
    transpose_cast<<<dim3(2048 / 64, 2048 / 64), blk, 0, stream>>>(Wo, WoT, 2048, 2048);

    gemm_bf16<true><<<dim3(2048 / 128, M / 128), blk, 0, stream>>>(hsb, WqT, Qb, 2048, 2048);
    gemm_bf16<true><<<dim3(1024 / 128, M / 128), blk, 0, stream>>>(hsb, WkvT, KVb, 1024, 2048);

    // RoPE: Q (scale folded), K (no scale). rowShift = 3 + log2(nH).
    rope_kernel<<<(M * NH * 8) / 256, blk, 0, stream>>>(Qb, 15, 7, 2048, qscale, M * NH * 8);
    rope_kernel<<<(M * NKV * 8) / 256, blk, 0, stream>>>(KVb, 3, 5, 1024, 1.0f, M * NKV * 8);

    vtrans<<<dim3(S / 64, B * NKV * 2), blk, 0, stream>>>(KVb, VT);

    attn_mfma<<<B * NKV * (S / 16), blk, 0, stream>>>(Qb, KVb, VT, AOb);

    gemm_bf16<false><<<dim3(2048 / 128, M / 128), blk, 0, stream>>>(AOb, WoT, out, 2048, 2048);
}

// Round 6
// 407.082 us; speedup vs baseline: 1.0117x; 1.0117x over previous
//
#include <hip/hip_runtime.h>
#include <math.h>

namespace {

typedef short s16;
typedef short s16x8 __attribute__((ext_vector_type(8)));
typedef float f32x4 __attribute__((ext_vector_type(4)));

constexpr int B   = 2;
constexpr int S   = 2048;
constexpr int H   = 2048;
constexpr int NH  = 16;
constexpr int NKV = 4;
constexpr int HD  = 128;
constexpr int WIN = 1024;
constexpr int M   = B * S;       // 4096

// ---- fp32 -> bf16 (RNE) as raw short ----
__device__ inline s16 f2bs(float x) {
    unsigned u = __float_as_uint(x);
    u += 0x7fffu + ((u >> 16) & 1u);
    return (s16)(u >> 16);
}
// ---- bf16 bits -> fp32 ----
__device__ inline float bs2f(s16 v) {
    return __uint_as_float(((unsigned)(unsigned short)v) << 16);
}

__device__ inline void gload_lds16(const void* g, void* l) {
    __builtin_amdgcn_global_load_lds(
        (const __attribute__((address_space(1))) void*)g,
        (__attribute__((address_space(3))) void*)l, 16, 0, 0);
}

// ---------- fp32 -> bf16 cast, 8 elems/thread ----------
__global__ __launch_bounds__(256) void cast_kernel(const float* __restrict__ X,
                                                   s16* __restrict__ Y, int n8) {
    int i = blockIdx.x * 256 + threadIdx.x;
    if (i >= n8) return;
    const float4* p = (const float4*)X + (size_t)i * 2;
    float4 a = p[0], b = p[1];
    s16x8 v;
    v[0] = f2bs(a.x); v[1] = f2bs(a.y); v[2] = f2bs(a.z); v[3] = f2bs(a.w);
    v[4] = f2bs(b.x); v[5] = f2bs(b.y); v[6] = f2bs(b.z); v[7] = f2bs(b.w);
    *(s16x8*)(Y + (size_t)i * 8) = v;
}

// ---------- W[K][N] fp32 -> WT[N][K] bf16 ----------
__global__ __launch_bounds__(256) void transpose_cast(const float* __restrict__ W,
                                                      s16* __restrict__ WT,
                                                      int K, int N) {
    __shared__ float tile[64][65];
    int c = threadIdx.x & 63, r4 = threadIdx.x >> 6;
    int nb = blockIdx.x * 64, kb = blockIdx.y * 64;
    #pragma unroll
    for (int i = 0; i < 16; ++i) {
        int r = r4 + i * 4;
        tile[r][c] = W[(size_t)(kb + r) * N + nb + c];
    }
    __syncthreads();
    #pragma unroll
    for (int i = 0; i < 16; ++i) {
        int r = r4 + i * 4;
        WT[(size_t)(nb + r) * K + kb + c] = f2bs(tile[c][r]);
    }
}

// ---------- bf16 MFMA GEMM: C[M,N] = A[M,K] @ BT[N,K]^T ----------
// 128x128 tile, BK=32, 4 waves (2x2), 4x4 16x16x32 frags per wave.
// LDS XOR-swizzled at 16B granularity (superrow=128B, slot'=slot^(sr&7)).
template <bool BF16OUT>
__global__ __launch_bounds__(256) void gemm_bf16(const s16* __restrict__ A,
                                                 const s16* __restrict__ BT,
                                                 void* __restrict__ Cv,
                                                 int Ndim, int Kdim) {
    __shared__ __align__(16) s16 As[128 * 32];
    __shared__ __align__(16) s16 Bs[128 * 32];

    const int t    = threadIdx.x;
    const int lane = t & 63;
    const int wid  = t >> 6;
    const int wr   = wid >> 1;
    const int wc   = wid & 1;
    const int rowBase = blockIdx.y * 128;
    const int colBase = blockIdx.x * 128;

    const s16* Ab = A  + (size_t)rowBase * Kdim;
    const s16* Bb = BT + (size_t)colBase * Kdim;

    f32x4 acc[4][4];
    #pragma unroll
    for (int m = 0; m < 4; ++m)
        #pragma unroll
        for (int n = 0; n < 4; ++n)
            acc[m][n] = (f32x4)0.f;

    for (int k0 = 0; k0 < Kdim; k0 += 32) {
        #pragma unroll
        for (int i = 0; i < 2; ++i) {
            int lc = i * 256 + t;             // 16B chunk 0..511
            int sr = lc >> 3;                 // 128B superrow
            int cc = (lc & 7) ^ (sr & 7);     // source chunk in superrow
            int r  = (sr << 1) | (cc >> 2);
            int kg = cc & 3;
            const s16* ga = Ab + (size_t)r * Kdim + k0 + kg * 8;
            const s16* gb = Bb + (size_t)r * Kdim + k0 + kg * 8;
            char* la = (char*)As + i * 4096 + wid * 1024;
            char* lb = (char*)Bs + i * 4096 + wid * 1024;
            gload_lds16(ga, la);
            gload_lds16(gb, lb);
        }
        __syncthreads();

        s16x8 af[4], bfr[4];
        #pragma unroll
        for (int m = 0; m < 4; ++m) {
            int r  = wr * 64 + m * 16 + (lane & 15);
            int sr = r >> 1;
            int c  = ((r & 1) << 2) | (lane >> 4);
            int cs = c ^ (sr & 7);
            af[m] = *(const s16x8*)(As + sr * 64 + cs * 8);
        }
        #pragma unroll
        for (int n = 0; n < 4; ++n) {
            int r  = wc * 64 + n * 16 + (lane & 15);
            int sr = r >> 1;
            int c  = ((r & 1) << 2) | (lane >> 4);
            int cs = c ^ (sr & 7);
            bfr[n] = *(const s16x8*)(Bs + sr * 64 + cs * 8);
        }
        #pragma unroll
        for (int m = 0; m < 4; ++m)
            #pragma unroll
            for (int n = 0; n < 4; ++n)
                acc[m][n] = __builtin_amdgcn_mfma_f32_16x16x32_bf16(af[m], bfr[n], acc[m][n], 0, 0, 0);

        __syncthreads();
    }

    // C/D: col=lane&15, row=(lane>>4)*4+reg (m89-verified)
    #pragma unroll
    for (int m = 0; m < 4; ++m) {
        int row = rowBase + wr * 64 + m * 16 + ((lane >> 4) << 2);
        #pragma unroll
        for (int n = 0; n < 4; ++n) {
            int col = colBase + wc * 64 + n * 16 + (lane & 15);
            if (BF16OUT) {
                s16* cp = (s16*)Cv + (size_t)row * Ndim + col;
                #pragma unroll
                for (int j = 0; j < 4; ++j)
                    cp[(size_t)j * Ndim] = f2bs(acc[m][n][j]);
            } else {
                float* cp = (float*)Cv + (size_t)row * Ndim + col;
                #pragma unroll
                for (int j = 0; j < 4; ++j)
                    cp[(size_t)j * Ndim] = acc[m][n][j];
            }
        }
    }
}

// ---------- RoPE in-place on bf16, 8 j-values per thread ----------
__global__ __launch_bounds__(256) void rope_kernel(s16* __restrict__ X, int nHmask,
                                                   int rowShift, int rowStride,
                                                   float scale, int total) {
    int idx = blockIdx.x * 256 + threadIdx.x;
    if (idx >= total) return;
    int jc  = idx & 7;                 // j-chunk of 8
    int hh  = (idx >> 3) & nHmask;
    int row = idx >> rowShift;
    int s   = row & (S - 1);

    s16* base = X + (size_t)row * rowStride + hh * HD;
    s16x8 a = *(const s16x8*)(base + jc * 8);
    s16x8 b = *(const s16x8*)(base + 64 + jc * 8);
    s16x8 na, nb;
    #pragma unroll
    for (int i = 0; i < 8; ++i) {
        int j = jc * 8 + i;
        float f = (float)s * exp2f(-(float)j * 0.2076205059302203f);  // s*10000^(-j/64)
        float sn, c;
        __sincosf(f, &sn, &c);
        float x1 = bs2f(a[i]), x2 = bs2f(b[i]);
        na[i] = f2bs((x1 * c - x2 * sn) * scale);
        nb[i] = f2bs((x2 * c + x1 * sn) * scale);
    }
    *(s16x8*)(base + jc * 8) = na;
    *(s16x8*)(base + 64 + jc * 8) = nb;
}

// ---------- V transpose: KVb[M][1024] (V at col 512+kvh*128+d) -> VT[b][kvh][128][S] ----------
__global__ __launch_bounds__(256) void vtrans(const s16* __restrict__ KVb,
                                              s16* __restrict__ VT) {
    __shared__ s16 tl[64][72];
    const int t  = threadIdx.x;
    const int c8 = (t & 7) * 8;
    const int r  = t >> 3;
    const int s0 = blockIdx.x * 64;
    const int z  = blockIdx.y;
    const int bk = z >> 1;
    const int d0 = (z & 1) * 64;
    const int b  = bk >> 2, kvh = bk & 3;

    #pragma unroll
    for (int i = 0; i < 2; ++i) {
        int row = r + i * 32;
        *(s16x8*)&tl[row][c8] =
            *(const s16x8*)(KVb + (size_t)(b * S + s0 + row) * 1024 + 512 + kvh * HD + d0 + c8);
    }
    __syncthreads();
    #pragma unroll
    for (int i = 0; i < 2; ++i) {
        int drow = r + i * 32;
        s16x8 v;
        #pragma unroll
        for (int k = 0; k < 8; ++k) v[k] = tl[c8 + k][drow];
        *(s16x8*)(VT + (size_t)(bk * 128 + d0 + drow) * S + s0 + c8) = v;
    }
}

// ---------- MFMA flash attention, 32-row q-tile/wave, 64-kv tiles, reg-staged pipeline ----------
// Block: 4 waves = 4 q-heads of one kv-group, same 32 q-rows. grid = B*NKV*(S/32) = 512.
// K LDS [64][128] swizzled slot^(r&15); V LDS [128][64] swizzled slot^(d&7);
// both staged global->reg (pre-swizzled source) then reg->LDS linear.
// P per-wave LDS (no cross-wave barrier needed). Q pre-scaled by 1/sqrt(128).
__global__ __launch_bounds__(256, 2) void attn_mfma(const s16* __restrict__ Q,
                                                    const s16* __restrict__ KV,
                                                    const s16* __restrict__ VT,
                                                    s16* __restrict__ O) {
    __shared__ __align__(16) s16 Kl[64 * 128];
    __shared__ __align__(16) s16 Vl[128 * 64];
    __shared__ __align__(16) s16 Pl[4][32 * 72];

    const int t    = threadIdx.x;
    const int lane = t & 63;
    const int wid  = t >> 6;
    const int g    = lane >> 4;
    const int cc   = lane & 15;
    const int bid  = blockIdx.x;
    const int qt   = bid & 63;
    const int kvh  = (bid >> 6) & 3;
    const int b    = bid >> 8;
    const int qbase = qt * 32;
    const int h    = kvh * 4 + wid;

    // Q A-frags: 2 row-tiles x 4 k-chunks
    s16x8 qf[2][4];
    #pragma unroll
    for (int tq = 0; tq < 2; ++tq)
        #pragma unroll
        for (int kc = 0; kc < 4; ++kc)
            qf[tq][kc] = *(const s16x8*)(Q + (size_t)(b * S + qbase + tq * 16 + cc) * 2048
                                           + h * HD + kc * 32 + g * 8);

    float m_[2][4], l_[2][4];
    f32x4 o_[2][8];
    #pragma unroll
    for (int tq = 0; tq < 2; ++tq) {
        #pragma unroll
        for (int j = 0; j < 4; ++j) { m_[tq][j] = -1e30f; l_[tq][j] = 0.f; }
        #pragma unroll
        for (int dt = 0; dt < 8; ++dt) o_[tq][dt] = (f32x4)0.f;
    }

    const int kvstart = qbase >= WIN ? qbase - WIN : 0;
    const int nt = (qbase + 32 - kvstart + 63) >> 6;

    int4 kreg[4], vreg[4];
    auto load_tile = [&](int kvb) {
        #pragma unroll
        for (int i = 0; i < 4; ++i) {
            int lc = i * 256 + t;              // K chunk 0..1023
            int r = lc >> 4, sl = lc & 15;
            int ch = sl ^ (r & 15);
            int kvr = kvb + r; if (kvr > S - 1) kvr = S - 1;
            kreg[i] = *(const int4*)(KV + (size_t)(b * S + kvr) * 1024 + kvh * HD + ch * 8);
        }
        #pragma unroll
        for (int i = 0; i < 4; ++i) {
            int lc = i * 256 + t;              // V chunk 0..1023
            int d = lc >> 3, sl = lc & 7;
            int ch = sl ^ (d & 7);
            int col = kvb + ch * 8; if (col > S - 8) col = S - 8;
            vreg[i] = *(const int4*)(VT + (size_t)((b * 4 + kvh) * HD + d) * S + col);
        }
    };
    auto write_tile = [&]() {
        #pragma unroll
        for (int i = 0; i < 4; ++i) {
            *(int4*)((char*)Kl + (size_t)(i * 256 + t) * 16) = kreg[i];
            *(int4*)((char*)Vl + (size_t)(i * 256 + t) * 16) = vreg[i];
        }
    };

    load_tile(kvstart);
    write_tile();
    __syncthreads();

    for (int it = 0; it < nt; ++it) {
        const int kvb = kvstart + it * 64;
        if (it + 1 < nt) load_tile(kvb + 64);   // async: latency hides under compute

        // ---- QK^T: S[32q][64kv] as 2x4 C-frags ----
        f32x4 sv[2][4];
        #pragma unroll
        for (int tq = 0; tq < 2; ++tq)
            #pragma unroll
            for (int n = 0; n < 4; ++n)
                sv[tq][n] = (f32x4)0.f;
        #pragma unroll
        for (int n = 0; n < 4; ++n) {
            int r = n * 16 + cc;
            #pragma unroll
            for (int kc = 0; kc < 4; ++kc) {
                int sl = (kc * 4 + g) ^ (r & 15);
                s16x8 kf = *(const s16x8*)(Kl + r * 128 + sl * 8);
                sv[0][n] = __builtin_amdgcn_mfma_f32_16x16x32_bf16(qf[0][kc], kf, sv[0][n], 0, 0, 0);
                sv[1][n] = __builtin_amdgcn_mfma_f32_16x16x32_bf16(qf[1][kc], kf, sv[1][n], 0, 0, 0);
            }
        }

        // ---- mask + online softmax (row q=qbase+tq*16+4g+j, col kv=kvb+n*16+cc) ----
        #pragma unroll
        for (int tq = 0; tq < 2; ++tq) {
            #pragma unroll
            for (int j = 0; j < 4; ++j) {
                int qp = qbase + tq * 16 + 4 * g + j;
                float p_[4];
                float mx = -1e30f;
                #pragma unroll
                for (int n = 0; n < 4; ++n) {
                    int dist = qp - (kvb + n * 16 + cc);
                    p_[n] = (dist >= 0 && dist <= WIN) ? sv[tq][n][j] : -1e30f;
                    mx = fmaxf(mx, p_[n]);
                }
                #pragma unroll
                for (int off = 1; off < 16; off <<= 1) mx = fmaxf(mx, __shfl_xor(mx, off));
                float mn = fmaxf(m_[tq][j], mx);
                float alpha = __expf(m_[tq][j] - mn);
                m_[tq][j] = mn;
                float ps = 0.f;
                #pragma unroll
                for (int n = 0; n < 4; ++n) { p_[n] = __expf(p_[n] - mn); ps += p_[n]; }
                #pragma unroll
                for (int off = 1; off < 16; off <<= 1) ps += __shfl_xor(ps, off);
                l_[tq][j] = l_[tq][j] * alpha + ps;
                int row = tq * 16 + 4 * g + j;
                #pragma unroll
                for (int n = 0; n < 4; ++n)
                    Pl[wid][row * 72 + n * 16 + cc] = f2bs(p_[n]);
                #pragma unroll
                for (int dt = 0; dt < 8; ++dt) o_[tq][dt][j] *= alpha;
            }
        }

        // ---- PV: O[32q][128d] += P[32q][64kv] @ V[64kv][128d] (P per-wave: no barrier) ----
        #pragma unroll
        for (int ks = 0; ks < 2; ++ks) {
            s16x8 pa0 = *(const s16x8*)(&Pl[wid][(0  + cc) * 72 + ks * 32 + g * 8]);
            s16x8 pa1 = *(const s16x8*)(&Pl[wid][(16 + cc) * 72 + ks * 32 + g * 8]);
            #pragma unroll
            for (int dt = 0; dt < 8; ++dt) {
                int d = dt * 16 + cc;
                int sl = (ks * 4 + g) ^ (d & 7);
                s16x8 vf = *(const s16x8*)(Vl + d * 64 + sl * 8);
                o_[0][dt] = __builtin_amdgcn_mfma_f32_16x16x32_bf16(pa0, vf, o_[0][dt], 0, 0, 0);
                o_[1][dt] = __builtin_amdgcn_mfma_f32_16x16x32_bf16(pa1, vf, o_[1][dt], 0, 0, 0);
            }
        }

        __syncthreads();               // all K/V LDS reads done
        if (it + 1 < nt) {
            write_tile();              // regs (arrived during compute) -> LDS
            __syncthreads();
        }
    }

    // ---- normalize + store ----
    #pragma unroll
    for (int tq = 0; tq < 2; ++tq) {
        #pragma unroll
        for (int j = 0; j < 4; ++j) {
            float inv = 1.0f / l_[tq][j];
            size_t rb = (size_t)(b * S + qbase + tq * 16 + 4 * g + j) * 2048 + h * HD;
            #pragma unroll
            for (int dt = 0; dt < 8; ++dt)
                O[rb + dt * 16 + cc] = f2bs(o_[tq][dt][j] * inv);
        }
    }
}

}  // namespace

extern "C" void kernel_launch(void* const* d_in, const int* in_sizes, int n_in,
                              void* d_out, int out_size, void* d_ws, size_t ws_size,
                              hipStream_t stream) {
    const float* hs = (const float*)d_in[0];
    const float* Wq = (const float*)d_in[1];
    const float* Wk = (const float*)d_in[2];
    const float* Wv = (const float*)d_in[3];
    const float* Wo = (const float*)d_in[4];
    float* out = (float*)d_out;

    char* p = (char*)d_ws;
    s16* hsb  = (s16*)p;  p += (size_t)M * 2048 * 2;
    s16* WqT  = (s16*)p;  p += (size_t)2048 * 2048 * 2;
    s16* WkvT = (s16*)p;  p += (size_t)1024 * 2048 * 2;
    s16* WoT  = (s16*)p;  p += (size_t)2048 * 2048 * 2;
    s16* Qb   = (s16*)p;  p += (size_t)M * 2048 * 2;
    s16* KVb  = (s16*)p;  p += (size_t)M * 1024 * 2;
    s16* VT   = (s16*)p;
    s16* AOb  = hsb;   // reuse after projections

    dim3 blk(256);
    const float qscale = 0.08838834764831845f;  // 1/sqrt(128)

    cast_kernel<<<(M * H / 8 + 255) / 256, blk, 0, stream>>>(hs, hsb, M * H / 8);
    transpose_cast<<<dim3(2048 / 64, 2048 / 64), blk, 0, stream>>>(Wq, WqT, 2048, 2048);
    transpose_cast<<<dim3(512 / 64, 2048 / 64), blk, 0, stream>>>(Wk, WkvT, 2048, 512);
    transpose_cast<<<dim3(512 / 64, 2048 / 64), blk, 0, stream>>>(Wv, WkvT + (size_t)512 * 2048, 2048, 512);
    transpose_cast<<<dim3(2048 / 64, 2048 / 64), blk, 0, stream>>>(Wo, WoT, 2048, 2048);

    gemm_bf16<true><<<dim3(2048 / 128, M / 128), blk, 0, stream>>>(hsb, WqT, Qb, 2048, 2048);
    gemm_bf16<true><<<dim3(1024 / 128, M / 128), blk, 0, stream>>>(hsb, WkvT, KVb, 1024, 2048);

    rope_kernel<<<(M * NH * 8) / 256, blk, 0, stream>>>(Qb, 15, 7, 2048, qscale, M * NH * 8);
    rope_kernel<<<(M * NKV * 8) / 256, blk, 0, stream>>>(KVb, 3, 5, 1024, 1.0f, M * NKV * 8);

    vtrans<<<dim3(S / 64, B * NKV * 2), blk, 0, stream>>>(KVb, VT);

    attn_mfma<<<B * NKV * (S / 32), blk, 0, stream>>>(Qb, KVb, VT, AOb);

    gemm_bf16<false><<<dim3(2048 / 128, M / 128), blk, 0, stream>>>(AOb, WoT, out, 2048, 2048);
}